// Round 5
// baseline (108.072 us; speedup 1.0000x reference)
//
#include <hip/hip_runtime.h>

// Ca_Aware_Embedder: distogram one-hot -> linear embed, fused.
// out[pair, c] = W[c, bin(pair)] + b[c], where bin() may be "none" -> b[c].
// Write-bandwidth-bound: 1024*1024*128 fp32 = 536.9 MB out. Floor ~80 us at
// the fill-kernel's demonstrated 6.75 TB/s store rate.
//
// R5: 1024 blocks (4/CU), one full row per block -> half the per-block
// prologues (W staging + barrier) of R4. Hot loop unchanged:
// {ds_read bin, ds_read_b128 Wt row, nontemporal dwordx4 store}.

typedef float f32x4 __attribute__((ext_vector_type(4)));

constexpr int N_RES = 1024;
constexpr int C_Z = 128;
constexpr int NO_BINS = 15;
constexpr int THREADS = 256;
constexpr int BLOCKS = N_RES;                              // 1024 = 4/CU
constexpr int PAIRS_PER_ITER = THREADS / 32;               // 8
constexpr int PAIRS_PER_BLOCK = N_RES;                     // one full row
constexpr int ITERS = PAIRS_PER_BLOCK / PAIRS_PER_ITER;    // 128
constexpr float INF_UPPER = 100000000.0f;

__global__ __launch_bounds__(THREADS) void ca_embedder_kernel(
    const float* __restrict__ x,   // [N_RES, 3]
    const float* __restrict__ W,   // [C_Z, NO_BINS]
    const float* __restrict__ b,   // [C_Z]
    float* __restrict__ out)       // [N_RES, N_RES, C_Z]
{
    __shared__ float Wt[NO_BINS + 1][C_Z];   // Wt[k][c] = W[c][k] + b[c]; row 15 = b
    __shared__ int sbin[PAIRS_PER_BLOCK];

    // Stage W^T (+ b) into LDS once per block.
    for (int idx = threadIdx.x; idx < C_Z * NO_BINS; idx += THREADS) {
        int c = idx / NO_BINS;
        int k = idx - c * NO_BINS;
        Wt[k][c] = W[idx] + b[c];
    }
    if (threadIdx.x < C_Z) {
        Wt[NO_BINS][threadIdx.x] = b[threadIdx.x];
    }

    const int i = blockIdx.x;                    // row index
    const size_t base = (size_t)i * N_RES;       // first pair of this row
    const float xi0 = x[3 * i + 0];
    const float xi1 = x[3 * i + 1];
    const float xi2 = x[3 * i + 2];

    // Bin pre-pass: 1024 bins, 4 per thread, exact reference semantics.
    for (int p = threadIdx.x; p < PAIRS_PER_BLOCK; p += THREADS) {
        const int j = p;
        const float dx = xi0 - x[3 * j + 0];
        const float dy = xi1 - x[3 * j + 1];
        const float dz = xi2 - x[3 * j + 2];
        const float d = dx * dx + dy * dy + dz * dz;

        int bin = NO_BINS;  // "no bin" -> b row
#pragma unroll
        for (int k = 0; k < NO_BINS; ++k) {
            const float blo = 3.25f + 1.25f * (float)k;
            const float lo = blo * blo;
            const float bhi = 3.25f + 1.25f * (float)(k + 1);
            const float hi = (k == NO_BINS - 1) ? INF_UPPER : bhi * bhi;
            if (d > lo && d < hi) bin = k;   // strict, matches reference
        }
        sbin[p] = bin;
    }
    __syncthreads();

    // Pure streaming loop: {bin broadcast read, Wt row read, nt store}.
    const int lp = threadIdx.x >> 5;     // local pair within iteration, 0..7
    const int lane = threadIdx.x & 31;   // channel quad, 0..31
    f32x4* __restrict__ out4 = reinterpret_cast<f32x4*>(out) + base * (C_Z / 4);

#pragma unroll 4
    for (int it = 0; it < ITERS; ++it) {
        const int p = it * PAIRS_PER_ITER + lp;
        const int bin = sbin[p];
        const f32x4 v = *reinterpret_cast<const f32x4*>(&Wt[bin][lane * 4]);
        __builtin_nontemporal_store(v, &out4[(size_t)p * (C_Z / 4) + lane]);
    }
}

extern "C" void kernel_launch(void* const* d_in, const int* in_sizes, int n_in,
                              void* d_out, int out_size, void* d_ws, size_t ws_size,
                              hipStream_t stream) {
    const float* x = (const float*)d_in[0];
    const float* W = (const float*)d_in[1];
    const float* b = (const float*)d_in[2];
    float* out = (float*)d_out;

    ca_embedder_kernel<<<dim3(BLOCKS), dim3(THREADS), 0, stream>>>(x, W, b, out);
}

// Round 6
// 98.967 us; speedup vs baseline: 1.0920x; 1.0920x over previous
//
#include <hip/hip_runtime.h>

// Ca_Aware_Embedder: distogram one-hot -> linear embed, fused.
// out[pair, c] = W[c, bin(pair)] + b[c], where bin() may be "none" -> b[c].
// Write-bandwidth-bound: 1024*1024*128 fp32 = 536.9 MB out. Floor ~80 us at
// the fill-kernel's demonstrated 6.75 TB/s store rate (plain stores!).
//
// R6: exact A/B vs R4 — plain store instead of nontemporal. The rocclr fill
// kernels hit 84% of peak with PLAIN stores; nt's sign was never isolated
// (R2->R4 changed slim-loop and nt together).
// R5 lesson: 8 blocks/CU (32 waves) needed — store concurrency, not
// prologue count, is what matters. Keep 2048 blocks x 256 threads.

typedef float f32x4 __attribute__((ext_vector_type(4)));

constexpr int N_RES = 1024;
constexpr int C_Z = 128;
constexpr int NO_BINS = 15;
constexpr int THREADS = 256;
constexpr int BLOCKS = 2048;                               // 8 blocks/CU
constexpr int PAIRS_PER_ITER = THREADS / 32;               // 8
constexpr int PAIRS_PER_BLOCK = (N_RES * N_RES) / BLOCKS;  // 512 (half a row)
constexpr int ITERS = PAIRS_PER_BLOCK / PAIRS_PER_ITER;    // 64
constexpr float INF_UPPER = 100000000.0f;

__global__ __launch_bounds__(THREADS) void ca_embedder_kernel(
    const float* __restrict__ x,   // [N_RES, 3]
    const float* __restrict__ W,   // [C_Z, NO_BINS]
    const float* __restrict__ b,   // [C_Z]
    float* __restrict__ out)       // [N_RES, N_RES, C_Z]
{
    __shared__ float Wt[NO_BINS + 1][C_Z];   // Wt[k][c] = W[c][k] + b[c]; row 15 = b
    __shared__ int sbin[PAIRS_PER_BLOCK];

    // Stage W^T (+ b) into LDS once per block.
    for (int idx = threadIdx.x; idx < C_Z * NO_BINS; idx += THREADS) {
        int c = idx / NO_BINS;
        int k = idx - c * NO_BINS;
        Wt[k][c] = W[idx] + b[c];
    }
    if (threadIdx.x < C_Z) {
        Wt[NO_BINS][threadIdx.x] = b[threadIdx.x];
    }

    const size_t base = (size_t)blockIdx.x * PAIRS_PER_BLOCK;
    // All 512 pairs of this block share row i (512 divides 1024).
    const int i = (int)(base >> 10);
    const float xi0 = x[3 * i + 0];
    const float xi1 = x[3 * i + 1];
    const float xi2 = x[3 * i + 2];
    const int j0 = (int)(base & (N_RES - 1));

    // Bin pre-pass: 512 bins, 2 per thread, exact reference semantics.
    for (int p = threadIdx.x; p < PAIRS_PER_BLOCK; p += THREADS) {
        const int j = j0 + p;
        const float dx = xi0 - x[3 * j + 0];
        const float dy = xi1 - x[3 * j + 1];
        const float dz = xi2 - x[3 * j + 2];
        const float d = dx * dx + dy * dy + dz * dz;

        int bin = NO_BINS;  // "no bin" -> b row
#pragma unroll
        for (int k = 0; k < NO_BINS; ++k) {
            const float blo = 3.25f + 1.25f * (float)k;
            const float lo = blo * blo;
            const float bhi = 3.25f + 1.25f * (float)(k + 1);
            const float hi = (k == NO_BINS - 1) ? INF_UPPER : bhi * bhi;
            if (d > lo && d < hi) bin = k;   // strict, matches reference
        }
        sbin[p] = bin;
    }
    __syncthreads();

    // Pure streaming loop: {bin broadcast read, Wt row read, plain store}.
    const int lp = threadIdx.x >> 5;     // local pair within iteration, 0..7
    const int lane = threadIdx.x & 31;   // channel quad, 0..31
    f32x4* __restrict__ out4 = reinterpret_cast<f32x4*>(out) + base * (C_Z / 4);

#pragma unroll 4
    for (int it = 0; it < ITERS; ++it) {
        const int p = it * PAIRS_PER_ITER + lp;
        const int bin = sbin[p];
        const f32x4 v = *reinterpret_cast<const f32x4*>(&Wt[bin][lane * 4]);
        out4[(size_t)p * (C_Z / 4) + lane] = v;
    }
}

extern "C" void kernel_launch(void* const* d_in, const int* in_sizes, int n_in,
                              void* d_out, int out_size, void* d_ws, size_t ws_size,
                              hipStream_t stream) {
    const float* x = (const float*)d_in[0];
    const float* W = (const float*)d_in[1];
    const float* b = (const float*)d_in[2];
    float* out = (float*)d_out;

    ca_embedder_kernel<<<dim3(BLOCKS), dim3(THREADS), 0, stream>>>(x, W, b, out);
}

// Round 7
// 94.818 us; speedup vs baseline: 1.1398x; 1.0438x over previous
//
#include <hip/hip_runtime.h>

// Ca_Aware_Embedder: distogram one-hot -> linear embed, fused.
// out[pair, c] = W[c, bin(pair)] + b[c], where bin() may be "none" -> b[c].
// Write-bandwidth-bound: 1024*1024*128 fp32 = 536.9 MB out. Demonstrated
// plain-store ceiling (rocclr fill): 6.7-6.9 TB/s -> ~80 us floor + ~6-9 us
// launch/ramp. R6 = 99.0 us (5.42 TB/s).
//
// R7: shorten the per-store LDS chain. Bins packed as bytes; transposed
// pair assignment (p = lp*64 + g*8 + k) so one broadcast ds_read_b64 feeds
// 8 stores. Inner 8 fully unrolled, static register selection (no runtime-
// indexed arrays -> no scratch). Plain dwordx4 stores (R6: nt was harmful).

typedef float f32x4 __attribute__((ext_vector_type(4)));

constexpr int N_RES = 1024;
constexpr int C_Z = 128;
constexpr int NO_BINS = 15;
constexpr int THREADS = 256;
constexpr int BLOCKS = 2048;                               // 8 blocks/CU
constexpr int PAIRS_PER_BLOCK = (N_RES * N_RES) / BLOCKS;  // 512 (half a row)
constexpr float INF_UPPER = 100000000.0f;

__global__ __launch_bounds__(THREADS) void ca_embedder_kernel(
    const float* __restrict__ x,   // [N_RES, 3]
    const float* __restrict__ W,   // [C_Z, NO_BINS]
    const float* __restrict__ b,   // [C_Z]
    float* __restrict__ out)       // [N_RES, N_RES, C_Z]
{
    __shared__ float Wt[NO_BINS + 1][C_Z];       // Wt[k][c] = W[c][k] + b[c]; row 15 = b
    __shared__ unsigned char sbin8[PAIRS_PER_BLOCK];

    // Stage W^T (+ b) into LDS once per block.
    for (int idx = threadIdx.x; idx < C_Z * NO_BINS; idx += THREADS) {
        int c = idx / NO_BINS;
        int k = idx - c * NO_BINS;
        Wt[k][c] = W[idx] + b[c];
    }
    if (threadIdx.x < C_Z) {
        Wt[NO_BINS][threadIdx.x] = b[threadIdx.x];
    }

    const size_t base = (size_t)blockIdx.x * PAIRS_PER_BLOCK;
    // All 512 pairs of this block share row i (512 divides 1024).
    const int i = (int)(base >> 10);
    const float xi0 = x[3 * i + 0];
    const float xi1 = x[3 * i + 1];
    const float xi2 = x[3 * i + 2];
    const int j0 = (int)(base & (N_RES - 1));

    // Bin pre-pass: 512 bins, 2 per thread, exact reference semantics.
    for (int p = threadIdx.x; p < PAIRS_PER_BLOCK; p += THREADS) {
        const int j = j0 + p;
        const float dx = xi0 - x[3 * j + 0];
        const float dy = xi1 - x[3 * j + 1];
        const float dz = xi2 - x[3 * j + 2];
        const float d = dx * dx + dy * dy + dz * dz;

        int bin = NO_BINS;  // "no bin" -> b row
#pragma unroll
        for (int k = 0; k < NO_BINS; ++k) {
            const float blo = 3.25f + 1.25f * (float)k;
            const float lo = blo * blo;
            const float bhi = 3.25f + 1.25f * (float)(k + 1);
            const float hi = (k == NO_BINS - 1) ? INF_UPPER : bhi * bhi;
            if (d > lo && d < hi) bin = k;   // strict, matches reference
        }
        sbin8[p] = (unsigned char)bin;
    }
    __syncthreads();

    // Streaming loop. Group g of 8 pairs: one broadcast ds_read_b64 of 8
    // bin bytes, then 8x {ds_read_b128 Wt row, plain dwordx4 store}.
    const int lp = threadIdx.x >> 5;     // pair-group, 0..7 (owns pairs lp*64..lp*64+63)
    const int lane = threadIdx.x & 31;   // channel quad, 0..31
    f32x4* __restrict__ po =
        reinterpret_cast<f32x4*>(out) + (base + (size_t)lp * 64) * (C_Z / 4) + lane;

    for (int g = 0; g < 8; ++g) {
        const uint2 w2 = *reinterpret_cast<const uint2*>(&sbin8[lp * 64 + g * 8]);
#pragma unroll
        for (int k = 0; k < 8; ++k) {
            const unsigned int w = (k < 4) ? w2.x : w2.y;         // static select
            const int bin = (w >> ((k & 3) * 8)) & 0xFF;
            const f32x4 v = *reinterpret_cast<const f32x4*>(&Wt[bin][lane * 4]);
            po[(size_t)(g * 8 + k) * (C_Z / 4)] = v;
        }
    }
}

extern "C" void kernel_launch(void* const* d_in, const int* in_sizes, int n_in,
                              void* d_out, int out_size, void* d_ws, size_t ws_size,
                              hipStream_t stream) {
    const float* x = (const float*)d_in[0];
    const float* W = (const float*)d_in[1];
    const float* b = (const float*)d_in[2];
    float* out = (float*)d_out;

    ca_embedder_kernel<<<dim3(BLOCKS), dim3(THREADS), 0, stream>>>(x, W, b, out);
}